// Round 4
// baseline (293.829 us; speedup 1.0000x reference)
//
#include <hip/hip_runtime.h>
#include <hip/hip_bf16.h>

#define BB 64
#define TT 1024
#define CHN 256
#define VV 32000
#define EE 64
#define LL 128
#define NC1 250      // k1 k-chunks (250*128 = 32000)
#define KC1 128
#define TS 8         // attention t-chunks (128 t each)

typedef unsigned short u16;
typedef unsigned int u32;

__device__ __forceinline__ float fast_rcp(float x) { return __builtin_amdgcn_rcpf(x); }
__device__ __forceinline__ float tanh_fast(float y) {
    float e = __expf(2.0f * y);              // inf/0 limits give +-1 correctly
    return 1.0f - 2.0f * fast_rcp(1.0f + e);
}
__device__ __forceinline__ float sigmoid_fast(float x) {
    return fast_rcp(1.0f + __expf(-x));
}

// ---------------- K1: prev_char[64,32000] @ Wc[32000,64] -> part[250][64][64] --------
// lane=e (coalesced W loads), A reads wave-uniform -> s_load, 8 b-acc per lane.
__global__ __launch_bounds__(512) void k1_stage1(const float* __restrict__ A,
                                                 const float* __restrict__ Wc,
                                                 float* __restrict__ part) {
    const int blk = blockIdx.x;
    const int k0 = blk * KC1;
    const int e  = threadIdx.x & 63;
    const int b0 = __builtin_amdgcn_readfirstlane(threadIdx.x >> 6) * 8;

    float acc[8];
    #pragma unroll
    for (int i = 0; i < 8; ++i) acc[i] = 0.0f;

    const float* Arow = A + (size_t)b0 * VV + k0;
    #pragma unroll 4
    for (int k = 0; k < KC1; ++k) {
        float wt = Wc[(size_t)(k0 + k) * EE + e];        // 256B coalesced per wave
        #pragma unroll
        for (int i = 0; i < 8; ++i) {
            float a = Arow[(size_t)i * VV + k];           // wave-uniform -> s_load
            acc[i] = fmaf(a, wt, acc[i]);
        }
    }
    float* dst = part + (size_t)blk * (BB * EE) + b0 * EE + e;
    #pragma unroll
    for (int i = 0; i < 8; ++i) dst[i * EE] = acc[i];
}

// ---------------- K2: reduce part + pcv@Wct1, z-GEMM, gates, H_tfm -------------------
__global__ __launch_bounds__(512) void k2_lstm(const float* __restrict__ part,
    const float* __restrict__ pcv, const float* __restrict__ state_h,
    const float* __restrict__ state_c, const float* __restrict__ Wct1,
    const float* __restrict__ lstm_kernel, const float* __restrict__ lstm_rec,
    const float* __restrict__ W_h,
    float* __restrict__ out_newh, float* __restrict__ out_newc,
    float* __restrict__ At, float* __restrict__ Htfm) {
    __shared__ float red[8][EE];
    __shared__ float inp[EE];
    __shared__ float sh[LL];
    __shared__ float z[4 * LL];
    __shared__ float nh[LL];
    const int b = blockIdx.x;
    const int t = threadIdx.x;
    const int e  = t & 63;
    const int g  = t >> 6;          // 0..7

    // part-reduction (strided over 250 chunks) + Wct1 contribution (32 c's per group)
    {
        float s = 0.0f;
        for (int j = g; j < NC1; j += 8)
            s += part[(size_t)j * (BB * EE) + b * EE + e];
        const int c0 = g * 32;
        #pragma unroll 8
        for (int c = 0; c < 32; ++c)
            s = fmaf(pcv[b * CHN + c0 + c], Wct1[(size_t)(c0 + c) * EE + e], s);
        red[g][e] = s;
    }
    __syncthreads();
    if (t < EE) {
        float s = 0.0f;
        #pragma unroll
        for (int j = 0; j < 8; ++j) s += red[j][t];
        inp[t] = s;
    } else if (t >= 64 && t < 64 + LL) {
        sh[t - 64] = state_h[b * LL + (t - 64)];
    }
    __syncthreads();
    {
        float a = 0.0f;
        #pragma unroll 8
        for (int e2 = 0; e2 < EE; ++e2) a = fmaf(inp[e2], lstm_kernel[e2 * 512 + t], a);
        #pragma unroll 8
        for (int l = 0; l < LL; ++l) a = fmaf(sh[l], lstm_rec[l * 512 + t], a);
        z[t] = a;
    }
    __syncthreads();
    if (t < LL) {
        float zi = z[t], zf = z[LL + t], zg = z[2 * LL + t], zo = z[3 * LL + t];
        float ig = sigmoid_fast(zi);
        float fg = sigmoid_fast(zf);
        float gg = tanh_fast(zg);
        float og = sigmoid_fast(zo);
        float co = state_c[b * LL + t];
        float cn = fg * co + ig * gg;
        float hn = og * tanh_fast(cn);
        out_newc[b * LL + t] = fminf(fmaxf(cn, -10.0f), 10.0f);
        out_newh[b * LL + t] = hn;
        At[t * BB + b] = hn;           // At[k][b] layout for k5 scalar reads
        nh[t] = hn;
    }
    __syncthreads();
    if (t < CHN) {
        float a = 0.0f;
        #pragma unroll 8
        for (int l = 0; l < LL; ++l) a = fmaf(nh[l], W_h[l * CHN + t], a);
        Htfm[b * CHN + t] = a;
    }
}

// ---------------- K3: attention partials per (b, ts), LDS cross-wave reduce ----------
__global__ __launch_bounds__(256) void k3_attn(const float* __restrict__ F,
    const float* __restrict__ Htfm, const float* __restrict__ Vattn,
    float* __restrict__ pS, float* __restrict__ pW) {
    __shared__ float4 sS[256];
    __shared__ float4 sW[256];
    const int b    = blockIdx.x;
    const int ts   = blockIdx.y;
    const int lane = threadIdx.x & 63;
    const int w    = threadIdx.x >> 6;
    const int ch   = lane * 4;

    float4 h = *(const float4*)(Htfm + b * CHN + ch);
    float4 v = *(const float4*)(Vattn + ch);
    float s0 = 0, s1 = 0, s2 = 0, s3 = 0;
    float a0 = 0, a1 = 0, a2 = 0, a3 = 0;

    const float* Fp = F + ((size_t)b * TT + ts * (TT / TS) + w * 32) * CHN + ch;
    #pragma unroll 4
    for (int t = 0; t < 32; ++t) {
        float4 f = *(const float4*)(Fp + (size_t)t * CHN);
        float e0 = __expf(v.x * tanh_fast(h.x + f.x));
        float e1 = __expf(v.y * tanh_fast(h.y + f.y));
        float e2 = __expf(v.z * tanh_fast(h.z + f.z));
        float e3 = __expf(v.w * tanh_fast(h.w + f.w));
        s0 += e0; s1 += e1; s2 += e2; s3 += e3;
        a0 = fmaf(e0, f.x, a0); a1 = fmaf(e1, f.y, a1);
        a2 = fmaf(e2, f.z, a2); a3 = fmaf(e3, f.w, a3);
    }
    sS[threadIdx.x] = make_float4(s0, s1, s2, s3);
    sW[threadIdx.x] = make_float4(a0, a1, a2, a3);
    __syncthreads();
    if (threadIdx.x < 64) {
        float4 S = sS[threadIdx.x];
        float4 W = sW[threadIdx.x];
        #pragma unroll
        for (int j = 1; j < 4; ++j) {
            float4 s = sS[j * 64 + threadIdx.x];
            float4 q = sW[j * 64 + threadIdx.x];
            S.x += s.x; S.y += s.y; S.z += s.z; S.w += s.w;
            W.x += q.x; W.y += q.y; W.z += q.z; W.w += q.w;
        }
        int base = (b * TS + ts) * CHN + threadIdx.x * 4;
        *(float4*)(pS + base) = S;
        *(float4*)(pW + base) = W;
    }
}

// ---------------- K4: reduce TS chunks -> c_t; also zeroes rowsum --------------------
__global__ __launch_bounds__(256) void k4_combine(const float* __restrict__ pS,
    const float* __restrict__ pW, float* __restrict__ out_ct, float* __restrict__ At,
    float* __restrict__ rowsum) {
    const int b = blockIdx.x;
    const int ch = threadIdx.x;
    float S = 0.0f, W = 0.0f;
    #pragma unroll
    for (int j = 0; j < TS; ++j) {
        int idx = (b * TS + j) * CHN + ch;
        S += pS[idx];
        W += pW[idx];
    }
    float c = W / S;
    out_ct[b * CHN + ch] = c;
    At[(LL + ch) * BB + b] = c;
    if (b == 0 && ch < BB) rowsum[ch] = 0.0f;   // k5b's atomic target (runs later)
}

// ---------------- K5: logits = newh@Wo + c_t@Wct2 (raw f32 into O region) ------------
// 250 blocks x 8 waves; lane: 2 v (float2) x 8 b acc; At rows via s_load.
__global__ __launch_bounds__(512) void k5_logits(const float* __restrict__ Wo,
    const float* __restrict__ Wct2, const float* __restrict__ At,
    float* __restrict__ outO) {
    const int v  = blockIdx.x * 128 + (threadIdx.x & 63) * 2;
    const int b0 = __builtin_amdgcn_readfirstlane(threadIdx.x >> 6) * 8;
    float2 acc[8];
    #pragma unroll
    for (int i = 0; i < 8; ++i) acc[i] = make_float2(0.0f, 0.0f);

    #pragma unroll 4
    for (int k = 0; k < LL; ++k) {
        float2 wt = *(const float2*)(Wo + (size_t)k * VV + v);
        const float* a = At + k * BB + b0;        // 8 consecutive uniform floats
        #pragma unroll
        for (int i = 0; i < 8; ++i) {
            acc[i].x = fmaf(a[i], wt.x, acc[i].x);
            acc[i].y = fmaf(a[i], wt.y, acc[i].y);
        }
    }
    #pragma unroll 4
    for (int k = 0; k < CHN; ++k) {
        float2 wt = *(const float2*)(Wct2 + (size_t)k * VV + v);
        const float* a = At + (LL + k) * BB + b0;
        #pragma unroll
        for (int i = 0; i < 8; ++i) {
            acc[i].x = fmaf(a[i], wt.x, acc[i].x);
            acc[i].y = fmaf(a[i], wt.y, acc[i].y);
        }
    }
    #pragma unroll
    for (int i = 0; i < 8; ++i)
        *(float2*)(outO + (size_t)(b0 + i) * VV + v) = acc[i];
}

// ---------------- K5b: per-row-chunk exp-sum -> atomic rowsum[64] --------------------
__global__ __launch_bounds__(256) void k5b_expsum(const float* __restrict__ O,
                                                  float* __restrict__ rowsum) {
    __shared__ float red[256];
    const int b = blockIdx.x;
    const int c = blockIdx.y;                 // 4 chunks of 2000 float4
    const int t = threadIdx.x;
    const float4* row4 = (const float4*)(O + (size_t)b * VV);

    float s = 0.0f;
    for (int i = c * 2000 + t; i < (c + 1) * 2000; i += 256) {
        float4 f = row4[i];
        s += __expf(f.x) + __expf(f.y) + __expf(f.z) + __expf(f.w);
    }
    red[t] = s;
    __syncthreads();
    for (int off = 128; off > 0; off >>= 1) {
        if (t < off) red[t] += red[t + off];
        __syncthreads();
    }
    if (t == 0) atomicAdd(&rowsum[b], red[0]);
}

// ---------------- K5c: normalize: out = exp(l) / rowsum[row] -------------------------
__global__ __launch_bounds__(256) void k5c_norm(float* __restrict__ O,
                                                const float* __restrict__ rowsum) {
    const int gid = blockIdx.x * 256 + threadIdx.x;      // 512000 float4's
    float4* O4 = (float4*)O;
    const u32 row = ((u32)gid * 4u) / (u32)VV;
    const float inv = fast_rcp(rowsum[row]);
    float4 f = O4[gid];
    f.x = __expf(f.x) * inv;
    f.y = __expf(f.y) * inv;
    f.z = __expf(f.z) * inv;
    f.w = __expf(f.w) * inv;
    O4[gid] = f;
}

extern "C" void kernel_launch(void* const* d_in, const int* in_sizes, int n_in,
                              void* d_out, int out_size, void* d_ws, size_t ws_size,
                              hipStream_t stream) {
    (void)in_sizes; (void)n_in; (void)out_size; (void)ws_size;
    const float* pcv       = (const float*)d_in[0];
    const float* F         = (const float*)d_in[1];
    const float* prev_char = (const float*)d_in[2];
    const float* state_h   = (const float*)d_in[3];
    const float* state_c   = (const float*)d_in[4];
    const float* Wc        = (const float*)d_in[5];
    const float* Wct1      = (const float*)d_in[6];
    const float* Wo        = (const float*)d_in[7];
    const float* Wct2      = (const float*)d_in[8];
    const float* lstm_k    = (const float*)d_in[9];
    const float* lstm_r    = (const float*)d_in[10];
    const float* W_h       = (const float*)d_in[11];
    const float* Vattn     = (const float*)d_in[12];

    // outputs: float32, concatenated flat in return order
    float* outO  = (float*)d_out;                  // [64][32000]
    float* outCt = outO + (size_t)BB * VV;         // [64][256]
    float* outH  = outCt + (size_t)BB * CHN;       // [64][128]
    float* outC  = outH + (size_t)BB * LL;         // [64][128]

    float* ws     = (float*)d_ws;
    float* part   = ws;                            // 250*4096 = 1,024,000 f
    float* pS     = part + (size_t)NC1 * BB * EE;  // 64*8*256 = 131,072 f
    float* pW     = pS + (size_t)BB * TS * CHN;    // 131,072 f
    float* At     = pW + (size_t)BB * TS * CHN;    // 384*64   = 24,576 f
    float* Htfm   = At + (LL + CHN) * BB;          // 16,384 f
    float* rowsum = part;                          // aliases dead part[0..63] after k2

    hipLaunchKernelGGL(k1_stage1, dim3(NC1), dim3(512), 0, stream, prev_char, Wc, part);
    hipLaunchKernelGGL(k2_lstm, dim3(BB), dim3(512), 0, stream, part, pcv, state_h,
                       state_c, Wct1, lstm_k, lstm_r, W_h, outH, outC, At, Htfm);
    hipLaunchKernelGGL(k3_attn, dim3(BB, TS), dim3(256), 0, stream, F, Htfm, Vattn, pS, pW);
    hipLaunchKernelGGL(k4_combine, dim3(BB), dim3(256), 0, stream, pS, pW, outCt, At, rowsum);
    hipLaunchKernelGGL(k5_logits, dim3(VV / 128), dim3(512), 0, stream, Wo, Wct2, At, outO);
    hipLaunchKernelGGL(k5b_expsum, dim3(BB, 4), dim3(256), 0, stream, outO, rowsum);
    hipLaunchKernelGGL(k5c_norm, dim3((BB * VV / 4) / 256), dim3(256), 0, stream, outO, rowsum);
}

// Round 5
// 256.969 us; speedup vs baseline: 1.1434x; 1.1434x over previous
//
#include <hip/hip_runtime.h>
#include <hip/hip_bf16.h>

#define BB 64
#define TT 1024
#define CHN 256
#define VV 32000
#define EE 64
#define LL 128
#define NC1 250      // k1 k-chunks (250*128 = 32000)
#define KC1 128
#define TS 8         // attention t-chunks (128 t each)

typedef unsigned short u16;
typedef unsigned int u32;

__device__ __forceinline__ float fast_rcp(float x) { return __builtin_amdgcn_rcpf(x); }
__device__ __forceinline__ float tanh_fast(float y) {
    float e = __expf(2.0f * y);              // inf/0 limits give +-1 correctly
    return 1.0f - 2.0f * fast_rcp(1.0f + e);
}
__device__ __forceinline__ float sigmoid_fast(float x) {
    return fast_rcp(1.0f + __expf(-x));
}

// ---------------- K1: prev_char[64,32000] @ Wc[32000,64] -> part[250][64][64] --------
// grid (250 kc, 2 bhalf) x 256thr. lane=e; wave=8 b. Software-pipelined Wc prefetch
// (two 8-deep register buffers) keeps 8 loads in flight during every FMA block.
__global__ __launch_bounds__(256) void k1_stage1(const float* __restrict__ A,
                                                 const float* __restrict__ Wc,
                                                 float* __restrict__ part) {
    const int kc = blockIdx.x;
    const int k0 = kc * KC1;
    const int e  = threadIdx.x & 63;
    const int b0 = blockIdx.y * 32 + __builtin_amdgcn_readfirstlane(threadIdx.x >> 6) * 8;

    float acc[8];
    #pragma unroll
    for (int i = 0; i < 8; ++i) acc[i] = 0.0f;

    const float* W  = Wc + (size_t)k0 * EE + e;
    const float* Ar = A + (size_t)b0 * VV + k0;           // wave-uniform base
    float wa[8], wb[8];
    #pragma unroll
    for (int j = 0; j < 8; ++j) wa[j] = W[(size_t)j * EE];

    for (int k = 0; k < KC1; k += 16) {
        #pragma unroll
        for (int j = 0; j < 8; ++j) wb[j] = W[(size_t)(k + 8 + j) * EE];
        #pragma unroll
        for (int j = 0; j < 8; ++j) {
            #pragma unroll
            for (int i = 0; i < 8; ++i)
                acc[i] = fmaf(Ar[(size_t)i * VV + k + j], wa[j], acc[i]);   // s_load
        }
        if (k + 16 < KC1) {
            #pragma unroll
            for (int j = 0; j < 8; ++j) wa[j] = W[(size_t)(k + 16 + j) * EE];
        }
        #pragma unroll
        for (int j = 0; j < 8; ++j) {
            #pragma unroll
            for (int i = 0; i < 8; ++i)
                acc[i] = fmaf(Ar[(size_t)i * VV + k + 8 + j], wb[j], acc[i]);
        }
    }
    float* dst = part + (size_t)kc * (BB * EE) + b0 * EE + e;
    #pragma unroll
    for (int i = 0; i < 8; ++i) dst[i * EE] = acc[i];
}

// ---------------- K2: reduce part + pcv@Wct1, z-GEMM, gates, H_tfm -------------------
__global__ __launch_bounds__(512) void k2_lstm(const float* __restrict__ part,
    const float* __restrict__ pcv, const float* __restrict__ state_h,
    const float* __restrict__ state_c, const float* __restrict__ Wct1,
    const float* __restrict__ lstm_kernel, const float* __restrict__ lstm_rec,
    const float* __restrict__ W_h,
    float* __restrict__ out_newh, float* __restrict__ out_newc,
    float* __restrict__ At, float* __restrict__ Htfm) {
    __shared__ float red[8][EE];
    __shared__ float inp[EE];
    __shared__ float sh[LL];
    __shared__ float z[4 * LL];
    __shared__ float nh[LL];
    const int b = blockIdx.x;
    const int t = threadIdx.x;
    const int e  = t & 63;
    const int g  = t >> 6;          // 0..7

    {
        float s = 0.0f;
        for (int j = g; j < NC1; j += 8)
            s += part[(size_t)j * (BB * EE) + b * EE + e];
        const int c0 = g * 32;
        #pragma unroll 8
        for (int c = 0; c < 32; ++c)
            s = fmaf(pcv[b * CHN + c0 + c], Wct1[(size_t)(c0 + c) * EE + e], s);
        red[g][e] = s;
    }
    __syncthreads();
    if (t < EE) {
        float s = 0.0f;
        #pragma unroll
        for (int j = 0; j < 8; ++j) s += red[j][t];
        inp[t] = s;
    } else if (t >= 64 && t < 64 + LL) {
        sh[t - 64] = state_h[b * LL + (t - 64)];
    }
    __syncthreads();
    {
        float a = 0.0f;
        #pragma unroll 8
        for (int e2 = 0; e2 < EE; ++e2) a = fmaf(inp[e2], lstm_kernel[e2 * 512 + t], a);
        #pragma unroll 8
        for (int l = 0; l < LL; ++l) a = fmaf(sh[l], lstm_rec[l * 512 + t], a);
        z[t] = a;
    }
    __syncthreads();
    if (t < LL) {
        float zi = z[t], zf = z[LL + t], zg = z[2 * LL + t], zo = z[3 * LL + t];
        float ig = sigmoid_fast(zi);
        float fg = sigmoid_fast(zf);
        float gg = tanh_fast(zg);
        float og = sigmoid_fast(zo);
        float co = state_c[b * LL + t];
        float cn = fg * co + ig * gg;
        float hn = og * tanh_fast(cn);
        out_newc[b * LL + t] = fminf(fmaxf(cn, -10.0f), 10.0f);
        out_newh[b * LL + t] = hn;
        At[t * BB + b] = hn;           // At[k][b] layout for k5 scalar reads
        nh[t] = hn;
    }
    __syncthreads();
    if (t < CHN) {
        float a = 0.0f;
        #pragma unroll 8
        for (int l = 0; l < LL; ++l) a = fmaf(nh[l], W_h[l * CHN + t], a);
        Htfm[b * CHN + t] = a;
    }
}

// ---------------- K3: attention partials per (b, ts), LDS cross-wave reduce ----------
__global__ __launch_bounds__(256) void k3_attn(const float* __restrict__ F,
    const float* __restrict__ Htfm, const float* __restrict__ Vattn,
    float* __restrict__ pS, float* __restrict__ pW) {
    __shared__ float4 sS[256];
    __shared__ float4 sW[256];
    const int b    = blockIdx.x;
    const int ts   = blockIdx.y;
    const int lane = threadIdx.x & 63;
    const int w    = threadIdx.x >> 6;
    const int ch   = lane * 4;

    float4 h = *(const float4*)(Htfm + b * CHN + ch);
    float4 v = *(const float4*)(Vattn + ch);
    float s0 = 0, s1 = 0, s2 = 0, s3 = 0;
    float a0 = 0, a1 = 0, a2 = 0, a3 = 0;

    const float* Fp = F + ((size_t)b * TT + ts * (TT / TS) + w * 32) * CHN + ch;
    #pragma unroll 4
    for (int t = 0; t < 32; ++t) {
        float4 f = *(const float4*)(Fp + (size_t)t * CHN);
        float e0 = __expf(v.x * tanh_fast(h.x + f.x));
        float e1 = __expf(v.y * tanh_fast(h.y + f.y));
        float e2 = __expf(v.z * tanh_fast(h.z + f.z));
        float e3 = __expf(v.w * tanh_fast(h.w + f.w));
        s0 += e0; s1 += e1; s2 += e2; s3 += e3;
        a0 = fmaf(e0, f.x, a0); a1 = fmaf(e1, f.y, a1);
        a2 = fmaf(e2, f.z, a2); a3 = fmaf(e3, f.w, a3);
    }
    sS[threadIdx.x] = make_float4(s0, s1, s2, s3);
    sW[threadIdx.x] = make_float4(a0, a1, a2, a3);
    __syncthreads();
    if (threadIdx.x < 64) {
        float4 S = sS[threadIdx.x];
        float4 W = sW[threadIdx.x];
        #pragma unroll
        for (int j = 1; j < 4; ++j) {
            float4 s = sS[j * 64 + threadIdx.x];
            float4 q = sW[j * 64 + threadIdx.x];
            S.x += s.x; S.y += s.y; S.z += s.z; S.w += s.w;
            W.x += q.x; W.y += q.y; W.z += q.z; W.w += q.w;
        }
        int base = (b * TS + ts) * CHN + threadIdx.x * 4;
        *(float4*)(pS + base) = S;
        *(float4*)(pW + base) = W;
    }
}

// ---------------- K4: reduce TS chunks -> c_t; also zeroes rowsum --------------------
__global__ __launch_bounds__(256) void k4_combine(const float* __restrict__ pS,
    const float* __restrict__ pW, float* __restrict__ out_ct, float* __restrict__ At,
    float* __restrict__ rowsum) {
    const int b = blockIdx.x;
    const int ch = threadIdx.x;
    float S = 0.0f, W = 0.0f;
    #pragma unroll
    for (int j = 0; j < TS; ++j) {
        int idx = (b * TS + j) * CHN + ch;
        S += pS[idx];
        W += pW[idx];
    }
    float c = W / S;
    out_ct[b * CHN + ch] = c;
    At[(LL + ch) * BB + b] = c;
    if (b == 0 && ch < BB) rowsum[ch] = 0.0f;   // k5b's atomic target (runs later)
}

// ---------------- K5 helper: software-pipelined GEMV phase ---------------------------
// 8-deep double-buffered weight prefetch: 8 global loads always in flight.
__device__ __forceinline__ void k5_phase(const float* __restrict__ W, int kn,
    const float* __restrict__ Abase, float acc[8]) {
    float wa[8], wb[8];
    #pragma unroll
    for (int j = 0; j < 8; ++j) wa[j] = W[(size_t)j * VV];
    for (int k = 0; k < kn; k += 16) {
        #pragma unroll
        for (int j = 0; j < 8; ++j) wb[j] = W[(size_t)(k + 8 + j) * VV];
        #pragma unroll
        for (int j = 0; j < 8; ++j) {
            const float* a = Abase + (size_t)(k + j) * BB;       // s_load x8
            #pragma unroll
            for (int i = 0; i < 8; ++i) acc[i] = fmaf(a[i], wa[j], acc[i]);
        }
        if (k + 16 < kn) {
            #pragma unroll
            for (int j = 0; j < 8; ++j) wa[j] = W[(size_t)(k + 16 + j) * VV];
        }
        #pragma unroll
        for (int j = 0; j < 8; ++j) {
            const float* a = Abase + (size_t)(k + 8 + j) * BB;
            #pragma unroll
            for (int i = 0; i < 8; ++i) acc[i] = fmaf(a[i], wb[j], acc[i]);
        }
    }
}

// ---------------- K5: logits = newh@Wo + c_t@Wct2 ------------------------------------
// grid (500 v-tiles, 2 b-halves) x 256 thr -> 4000 waves (~39% occupancy).
__global__ __launch_bounds__(256) void k5_logits(const float* __restrict__ Wo,
    const float* __restrict__ Wct2, const float* __restrict__ At,
    float* __restrict__ outO) {
    const int v  = blockIdx.x * 64 + (threadIdx.x & 63);
    const int b0 = blockIdx.y * 32 + __builtin_amdgcn_readfirstlane(threadIdx.x >> 6) * 8;
    float acc[8];
    #pragma unroll
    for (int i = 0; i < 8; ++i) acc[i] = 0.0f;

    k5_phase(Wo + v, LL, At + b0, acc);
    k5_phase(Wct2 + v, CHN, At + (size_t)LL * BB + b0, acc);

    #pragma unroll
    for (int i = 0; i < 8; ++i) outO[(size_t)(b0 + i) * VV + v] = acc[i];
}

// ---------------- K5b: per-row-chunk exp-sum -> atomic rowsum[64] --------------------
__global__ __launch_bounds__(256) void k5b_expsum(const float* __restrict__ O,
                                                  float* __restrict__ rowsum) {
    __shared__ float red[256];
    const int b = blockIdx.x;
    const int c = blockIdx.y;                 // 4 chunks of 2000 float4
    const int t = threadIdx.x;
    const float4* row4 = (const float4*)(O + (size_t)b * VV);

    float s = 0.0f;
    for (int i = c * 2000 + t; i < (c + 1) * 2000; i += 256) {
        float4 f = row4[i];
        s += __expf(f.x) + __expf(f.y) + __expf(f.z) + __expf(f.w);
    }
    red[t] = s;
    __syncthreads();
    for (int off = 128; off > 0; off >>= 1) {
        if (t < off) red[t] += red[t + off];
        __syncthreads();
    }
    if (t == 0) atomicAdd(&rowsum[b], red[0]);
}

// ---------------- K5c: normalize: out = exp(l) / rowsum[row] -------------------------
__global__ __launch_bounds__(256) void k5c_norm(float* __restrict__ O,
                                                const float* __restrict__ rowsum) {
    const int gid = blockIdx.x * 256 + threadIdx.x;      // 512000 float4's
    float4* O4 = (float4*)O;
    const u32 row = ((u32)gid * 4u) / (u32)VV;
    const float inv = fast_rcp(rowsum[row]);
    float4 f = O4[gid];
    f.x = __expf(f.x) * inv;
    f.y = __expf(f.y) * inv;
    f.z = __expf(f.z) * inv;
    f.w = __expf(f.w) * inv;
    O4[gid] = f;
}

extern "C" void kernel_launch(void* const* d_in, const int* in_sizes, int n_in,
                              void* d_out, int out_size, void* d_ws, size_t ws_size,
                              hipStream_t stream) {
    (void)in_sizes; (void)n_in; (void)out_size; (void)ws_size;
    const float* pcv       = (const float*)d_in[0];
    const float* F         = (const float*)d_in[1];
    const float* prev_char = (const float*)d_in[2];
    const float* state_h   = (const float*)d_in[3];
    const float* state_c   = (const float*)d_in[4];
    const float* Wc        = (const float*)d_in[5];
    const float* Wct1      = (const float*)d_in[6];
    const float* Wo        = (const float*)d_in[7];
    const float* Wct2      = (const float*)d_in[8];
    const float* lstm_k    = (const float*)d_in[9];
    const float* lstm_r    = (const float*)d_in[10];
    const float* W_h       = (const float*)d_in[11];
    const float* Vattn     = (const float*)d_in[12];

    // outputs: float32, concatenated flat in return order
    float* outO  = (float*)d_out;                  // [64][32000]
    float* outCt = outO + (size_t)BB * VV;         // [64][256]
    float* outH  = outCt + (size_t)BB * CHN;       // [64][128]
    float* outC  = outH + (size_t)BB * LL;         // [64][128]

    float* ws     = (float*)d_ws;
    float* part   = ws;                            // 250*4096 = 1,024,000 f
    float* pS     = part + (size_t)NC1 * BB * EE;  // 64*8*256 = 131,072 f
    float* pW     = pS + (size_t)BB * TS * CHN;    // 131,072 f
    float* At     = pW + (size_t)BB * TS * CHN;    // 384*64   = 24,576 f
    float* Htfm   = At + (LL + CHN) * BB;          // 16,384 f
    float* rowsum = part;                          // aliases dead part[0..63] after k2

    hipLaunchKernelGGL(k1_stage1, dim3(NC1, 2), dim3(256), 0, stream, prev_char, Wc, part);
    hipLaunchKernelGGL(k2_lstm, dim3(BB), dim3(512), 0, stream, part, pcv, state_h,
                       state_c, Wct1, lstm_k, lstm_r, W_h, outH, outC, At, Htfm);
    hipLaunchKernelGGL(k3_attn, dim3(BB, TS), dim3(256), 0, stream, F, Htfm, Vattn, pS, pW);
    hipLaunchKernelGGL(k4_combine, dim3(BB), dim3(256), 0, stream, pS, pW, outCt, At, rowsum);
    hipLaunchKernelGGL(k5_logits, dim3(VV / 64, 2), dim3(256), 0, stream, Wo, Wct2, At, outO);
    hipLaunchKernelGGL(k5b_expsum, dim3(BB, 4), dim3(256), 0, stream, outO, rowsum);
    hipLaunchKernelGGL(k5c_norm, dim3((BB * VV / 4) / 256), dim3(256), 0, stream, outO, rowsum);
}